// Round 6
// baseline (2125.620 us; speedup 1.0000x reference)
//
#include <hip/hip_runtime.h>

#define NP 131072   // points
#define DD 128      // dims (GEMM K)
#define KK 256      // clusters (GEMM N)
#define MAXIT 8
#define TOLSQ (1e-4f * 1e-4f)
#define NSLICE 2    // dims split into 2 x 64 for accumulation
#define NCHUNK 64   // point chunks (2048 points each)
#define SLICE_D 64

typedef _Float16 half8 __attribute__((ext_vector_type(8)));
typedef float f32x4 __attribute__((ext_vector_type(4)));

// ws re-poisoned 0xAA before every timed call — every field below is written
// before it is read on every kernel_launch.  Total ~76.4 MB (round-4 proved
// >= 76.5 MB available).
struct Ws {
    float C[KK * DD];
    float newC[KK * DD];
    float cnorm[KK];
    float shiftsq;
    int done;
    int ilab[NP];                         // labels (int)
    int counts[KK];                       // per-cluster sizes (int, exact)
    float psums[NSLICE * NCHUNK * KK * SLICE_D];  // non-atomic partials, 8.4 MB
    // fp16 hi/lo planes, pre-swizzled into MFMA fragment order (16B aligned)
    alignas(16) _Float16 Csh[KK * DD];
    alignas(16) _Float16 Csl[KK * DD];
    alignas(16) _Float16 Xsh[(size_t)NP * DD];
    alignas(16) _Float16 Xsl[(size_t)NP * DD];
};

// C0 = X[init_idx]; zero done flag.  grid: KK x DD
__global__ void k_init(const float* __restrict__ X, const int* __restrict__ idx,
                       float* __restrict__ C, int* __restrict__ done) {
    int k = blockIdx.x, d = threadIdx.x;
    C[k * DD + d] = X[(size_t)idx[k] * DD + d];
    if (k == 0 && d == 0) *done = 0;
}

// Once per call: split X into fp16 hi/lo planes in A-fragment order.
// A-frag (16x16x32 f16): lane L of the wave owning 16-point group g16 at
// k-step ks holds X[g16*16 + (L&15)][ks*32 + (L>>4)*8 + j], j=0..7.
// Flat: Xs[(((g16*4)+ks)*64 + L)*8 + j].  grid: NP*DD/8/256 = 8192 blocks.
__global__ void k_split(const float* __restrict__ X, _Float16* __restrict__ Xh,
                        _Float16* __restrict__ Xl) {
    size_t idx = (size_t)blockIdx.x * 256 + threadIdx.x;  // one per 8 elems
    int lane = idx & 63;
    size_t g16k = idx >> 6;
    size_t point = (g16k >> 2) * 16 + (lane & 15);
    int dim0 = (int)(g16k & 3) * 32 + (lane >> 4) * 8;
    const f32x4* s4 = (const f32x4*)(X + point * DD + dim0);
    f32x4 a = s4[0], b = s4[1];
    half8 h, l;
#pragma unroll
    for (int j = 0; j < 4; j++) {
        _Float16 hi = (_Float16)a[j];
        h[j] = hi; l[j] = (_Float16)(a[j] - (float)hi);
    }
#pragma unroll
    for (int j = 0; j < 4; j++) {
        _Float16 hi = (_Float16)b[j];
        h[4 + j] = hi; l[4 + j] = (_Float16)(b[j] - (float)hi);
    }
    *(half8*)(Xh + idx * 8) = h;
    *(half8*)(Xl + idx * 8) = l;
}

// Initial prep: cnorm + hi/lo B-fragment planes for C0; zero counts.
// B-frag: lane L at (ks, cluster-tile ct) holds C[ct*16+(L&15)][ks*32+(L>>4)*8+j]
// -> flat ((ks*16+ct)*64 + L)*8 + j.  grid: KK x DD
__global__ void k_prep0(const float* __restrict__ C, float* __restrict__ cnorm,
                        _Float16* __restrict__ Ch, _Float16* __restrict__ Cl,
                        int* __restrict__ counts) {
    int k = blockIdx.x, d = threadIdx.x;
    float v = C[k * DD + d];
    _Float16 hi = (_Float16)v;
    int ct = k >> 4, l4 = k & 15, ks = d >> 5, q = (d >> 3) & 3, j = d & 7;
    size_t dst = ((size_t)(ks * 16 + ct) * 64 + (q * 16 + l4)) * 8 + j;
    Ch[dst] = hi;
    Cl[dst] = (_Float16)(v - (float)hi);
    __shared__ float red[DD];
    red[d] = v * v;
    __syncthreads();
    for (int s = DD / 2; s > 0; s >>= 1) {
        if (d < s) red[d] += red[d + s];
        __syncthreads();
    }
    if (d == 0) {
        cnorm[k] = red[0];
        counts[k] = 0;
    }
}

// MFMA assignment + per-block label histogram -> global counts.
// Each wave = 32 points x 256 clusters, fp16 hi/lo 3-term split, fp32 acc.
// Also zeroes shiftsq (stream-ordered: previous upprep already consumed it).
// grid: NP/128 x 256.
__global__ __launch_bounds__(256, 2) void k_assign(
    const _Float16* __restrict__ Xh, const _Float16* __restrict__ Xl,
    const _Float16* __restrict__ Ch, const _Float16* __restrict__ Cl,
    const float* __restrict__ cnorm, float* __restrict__ outlab,
    int* __restrict__ ilab, int* __restrict__ counts,
    float* __restrict__ shiftsq) {
    __shared__ int hist[KK];
    if (blockIdx.x == 0 && threadIdx.x == 0) *shiftsq = 0.0f;
    hist[threadIdx.x] = 0;

    const int wave = threadIdx.x >> 6;
    const int lane = threadIdx.x & 63;
    const int l4 = lane & 15, g = lane >> 4;
    const int g16 = blockIdx.x * 8 + wave * 2;

    f32x4 acc[2][16];
#pragma unroll
    for (int pg = 0; pg < 2; pg++)
#pragma unroll
        for (int ct = 0; ct < 16; ct++) acc[pg][ct] = (f32x4){0.f, 0.f, 0.f, 0.f};

#pragma unroll
    for (int ks = 0; ks < 4; ks++) {
        const size_t a0 = ((size_t)(g16 * 4 + ks) * 64 + lane) * 8;
        const size_t a1 = ((size_t)((g16 + 1) * 4 + ks) * 64 + lane) * 8;
        half8 ah0 = *(const half8*)(Xh + a0);
        half8 al0 = *(const half8*)(Xl + a0);
        half8 ah1 = *(const half8*)(Xh + a1);
        half8 al1 = *(const half8*)(Xl + a1);
#pragma unroll
        for (int ct = 0; ct < 16; ct++) {
            const size_t bo = ((size_t)(ks * 16 + ct) * 64 + lane) * 8;
            half8 bh = *(const half8*)(Ch + bo);
            half8 bl = *(const half8*)(Cl + bo);
            acc[0][ct] = __builtin_amdgcn_mfma_f32_16x16x32_f16(al0, bh, acc[0][ct], 0, 0, 0);
            acc[0][ct] = __builtin_amdgcn_mfma_f32_16x16x32_f16(ah0, bl, acc[0][ct], 0, 0, 0);
            acc[0][ct] = __builtin_amdgcn_mfma_f32_16x16x32_f16(ah0, bh, acc[0][ct], 0, 0, 0);
            acc[1][ct] = __builtin_amdgcn_mfma_f32_16x16x32_f16(al1, bh, acc[1][ct], 0, 0, 0);
            acc[1][ct] = __builtin_amdgcn_mfma_f32_16x16x32_f16(ah1, bl, acc[1][ct], 0, 0, 0);
            acc[1][ct] = __builtin_amdgcn_mfma_f32_16x16x32_f16(ah1, bh, acc[1][ct], 0, 0, 0);
        }
    }

    float cn[16];
#pragma unroll
    for (int ct = 0; ct < 16; ct++) cn[ct] = cnorm[ct * 16 + l4];

    // Packed argmin keys: (monotone(float) << 32) | cluster. NaN -> -inf so
    // NaN beats all finite values; low bits give np's first-index tie-break.
    unsigned long long best[2][4];
#pragma unroll
    for (int pg = 0; pg < 2; pg++)
#pragma unroll
        for (int r = 0; r < 4; r++) best[pg][r] = ~0ull;

#pragma unroll
    for (int pg = 0; pg < 2; pg++)
#pragma unroll
        for (int ct = 0; ct < 16; ct++)
#pragma unroll
            for (int r = 0; r < 4; r++) {
                float s = fmaf(-2.0f, acc[pg][ct][r], cn[ct]);
                if (__builtin_isnan(s)) s = -__builtin_inff();
                unsigned u = __float_as_uint(s);
                unsigned m = (u >> 31) ? ~u : (u ^ 0x80000000u);
                unsigned long long key =
                    ((unsigned long long)m << 32) | (unsigned)(ct * 16 + l4);
                if (key < best[pg][r]) best[pg][r] = key;
            }

    // reduce over the 16 cluster-column lanes (low 4 lane bits)
#pragma unroll
    for (int d = 1; d < 16; d <<= 1)
#pragma unroll
        for (int pg = 0; pg < 2; pg++)
#pragma unroll
            for (int r = 0; r < 4; r++) {
                unsigned long long o = __shfl_xor(best[pg][r], d, 64);
                if (o < best[pg][r]) best[pg][r] = o;
            }

    __syncthreads();  // hist zero visible
    if (l4 == 0) {
#pragma unroll
        for (int pg = 0; pg < 2; pg++)
#pragma unroll
            for (int r = 0; r < 4; r++) {
                int point = blockIdx.x * 128 + wave * 32 + pg * 16 + g * 4 + r;
                int lbl = (int)(best[pg][r] & 0x1ff);
                outlab[point] = (float)lbl;
                ilab[point] = lbl;
                atomicAdd(&hist[lbl], 1);
            }
    }
    __syncthreads();
    int h = hist[threadIdx.x];
    if (h) atomicAdd(&counts[threadIdx.x], h);
}

// Accumulation with CONVERGENT LDS atomics: lane = dim within a 64-dim slice,
// so each ds_add_f32 instruction touches 64 consecutive LDS words (2 lanes/
// bank = free, m136) instead of 64 divergent labels (~190 cyc, R4 lesson).
// Whole wave processes one point per step, unrolled x8 for load ILP.
// grid: dim3(NSLICE, NCHUNK) x 256
__global__ __launch_bounds__(256) void k_accum(
    const float* __restrict__ X, const int* __restrict__ lab,
    float* __restrict__ psums) {
    const int slice = blockIdx.x, chunk = blockIdx.y;
    const int t = threadIdx.x;
    const int wave = t >> 6, lane = t & 63;

    __shared__ float bins[KK * SLICE_D];  // 64 KB
    for (int i = t; i < KK * SLICE_D; i += 256) bins[i] = 0.0f;
    __syncthreads();

    const int ppw = NP / NCHUNK / 4;  // 512 points per wave
    int p = chunk * (NP / NCHUNK) + wave * ppw;
    const float* Xs = X + slice * SLICE_D + lane;

    for (int i = 0; i < ppw; i += 8) {
        float x0 = Xs[(size_t)(p + 0) * DD];
        float x1 = Xs[(size_t)(p + 1) * DD];
        float x2 = Xs[(size_t)(p + 2) * DD];
        float x3 = Xs[(size_t)(p + 3) * DD];
        float x4 = Xs[(size_t)(p + 4) * DD];
        float x5 = Xs[(size_t)(p + 5) * DD];
        float x6 = Xs[(size_t)(p + 6) * DD];
        float x7 = Xs[(size_t)(p + 7) * DD];
        int l0 = lab[p + 0], l1 = lab[p + 1], l2 = lab[p + 2], l3 = lab[p + 3];
        int l4_ = lab[p + 4], l5 = lab[p + 5], l6 = lab[p + 6], l7 = lab[p + 7];
        unsafeAtomicAdd(&bins[l0 * SLICE_D + lane], x0);
        unsafeAtomicAdd(&bins[l1 * SLICE_D + lane], x1);
        unsafeAtomicAdd(&bins[l2 * SLICE_D + lane], x2);
        unsafeAtomicAdd(&bins[l3 * SLICE_D + lane], x3);
        unsafeAtomicAdd(&bins[l4_ * SLICE_D + lane], x4);
        unsafeAtomicAdd(&bins[l5 * SLICE_D + lane], x5);
        unsafeAtomicAdd(&bins[l6 * SLICE_D + lane], x6);
        unsafeAtomicAdd(&bins[l7 * SLICE_D + lane], x7);
        p += 8;
    }
    __syncthreads();

    float* po = psums + (size_t)(slice * NCHUNK + chunk) * (KK * SLICE_D);
    for (int i = t; i < KK * SLICE_D; i += 256) po[i] = bins[i];
}

// Reduce NCHUNK partials -> newC = sums/counts (0/0 -> NaN, matching jnp);
// shift^2 block-reduced, one atomic per block.  grid: KK*DD/256 x 256
__global__ void k_reduce(const float* __restrict__ psums, const int* __restrict__ counts,
                         const float* __restrict__ C, float* __restrict__ newC,
                         float* __restrict__ shiftsq) {
    const int g = blockIdx.x * 256 + threadIdx.x;
    const int k = g >> 7, d = g & 127, sl = d >> 6, dd = d & 63;
    const int t = threadIdx.x;

    float s = 0.0f;
    const float* base = psums + (size_t)sl * NCHUNK * (KK * SLICE_D) + k * SLICE_D + dd;
    for (int c = 0; c < NCHUNK; c++) s += base[(size_t)c * (KK * SLICE_D)];

    float nc = s / (float)counts[k];
    newC[g] = nc;
    float diff = nc - C[g];

    __shared__ float red[256];
    red[t] = diff * diff;
    __syncthreads();
    for (int st = 128; st > 0; st >>= 1) {
        if (t < st) red[t] += red[t + st];
        __syncthreads();
    }
    if (t == 0) atomicAdd(shiftsq, red[0]);
}

// Fused convergence check + centroid update + next-iter prep (cnorm + hi/lo
// planes) + zero counts. NaN shiftsq -> not converged (jnp match). Benign
// done race: all blocks compute the same nd.  grid: KK/2 x 256.
__global__ void k_upprep(const float* __restrict__ newC, float* __restrict__ C,
                         const float* __restrict__ shiftsq, int* __restrict__ done,
                         float* __restrict__ cnorm, _Float16* __restrict__ Ch,
                         _Float16* __restrict__ Cl, int* __restrict__ counts) {
    const int t = threadIdx.x;
    const int k = blockIdx.x * 2 + (t >> 7);
    const int d = t & 127;
    float ss = *shiftsq;
    int nd = (*done != 0) || (ss < TOLSQ);
    float v = nd ? C[k * DD + d] : newC[k * DD + d];
    C[k * DD + d] = v;
    if (blockIdx.x == 0 && t == 0 && nd) *done = 1;
    if (d == 0) counts[k] = 0;

    _Float16 hi = (_Float16)v;
    int ct = k >> 4, l4 = k & 15, ks = d >> 5, q = (d >> 3) & 3, j = d & 7;
    size_t dst = ((size_t)(ks * 16 + ct) * 64 + (q * 16 + l4)) * 8 + j;
    Ch[dst] = hi;
    Cl[dst] = (_Float16)(v - (float)hi);

    __shared__ float red[256];
    red[t] = v * v;
    __syncthreads();
    for (int s = 64; s > 0; s >>= 1) {
        if ((t & 127) < s) red[t] += red[t + s];
        __syncthreads();
    }
    if (d == 0) cnorm[k] = red[t];
}

__global__ void k_final(const float* __restrict__ C, float* __restrict__ out) {
    int i = blockIdx.x * 256 + threadIdx.x;
    out[i] = C[i];
}

extern "C" void kernel_launch(void* const* d_in, const int* in_sizes, int n_in,
                              void* d_out, int out_size, void* d_ws, size_t ws_size,
                              hipStream_t stream) {
    const float* X = (const float*)d_in[0];
    const int* idx = (const int*)d_in[1];
    float* out = (float*)d_out;
    Ws* w = (Ws*)d_ws;

    k_init<<<KK, DD, 0, stream>>>(X, idx, w->C, &w->done);
    k_split<<<(int)((size_t)NP * DD / 8 / 256), 256, 0, stream>>>(X, w->Xsh, w->Xsl);
    k_prep0<<<KK, DD, 0, stream>>>(w->C, w->cnorm, w->Csh, w->Csl, w->counts);

    for (int it = 0; it < MAXIT; it++) {
        k_assign<<<NP / 128, 256, 0, stream>>>(w->Xsh, w->Xsl, w->Csh, w->Csl,
                                               w->cnorm, out, w->ilab, w->counts,
                                               &w->shiftsq);
        k_accum<<<dim3(NSLICE, NCHUNK), 256, 0, stream>>>(X, w->ilab, w->psums);
        k_reduce<<<KK * DD / 256, 256, 0, stream>>>(w->psums, w->counts, w->C,
                                                    w->newC, &w->shiftsq);
        k_upprep<<<KK / 2, 256, 0, stream>>>(w->newC, w->C, &w->shiftsq, &w->done,
                                             w->cnorm, w->Csh, w->Csl, w->counts);
    }

    k_final<<<KK * DD / 256, 256, 0, stream>>>(w->C, out + NP);
}

// Round 7
// 928.798 us; speedup vs baseline: 2.2886x; 2.2886x over previous
//
#include <hip/hip_runtime.h>

#define NP 131072   // points (= 2^17, label packs above bit 17)
#define DD 128      // dims (GEMM K)
#define KK 256      // clusters (GEMM N)
#define MAXIT 8
#define TOLSQ (1e-4f * 1e-4f)
#define POSB 256    // positions per k_sum block
#define UPIPE 8     // gather pipeline depth

typedef _Float16 half8 __attribute__((ext_vector_type(8)));
typedef float f32x4 __attribute__((ext_vector_type(4)));

// ws re-poisoned 0xAA before every timed call — every field below is written
// before it is read on every kernel_launch.
struct Ws {
    float C[KK * DD];
    float newC[KK * DD];
    float cnorm[KK];
    float sums[KK * DD];       // per-cluster coordinate sums (atomic-flushed)
    float shiftsq;
    int done;
    int ilab[NP];              // labels
    int counts[KK];            // per-cluster sizes (exact, int)
    int cursor[KK];            // global reservation cursors (zeroed per iter)
    int ordlab[NP];            // cluster-sorted: point | (label<<17)
    // fp16 hi/lo planes, pre-swizzled into MFMA fragment order (16B aligned)
    alignas(16) _Float16 Csh[KK * DD];
    alignas(16) _Float16 Csl[KK * DD];
    alignas(16) _Float16 Xsh[(size_t)NP * DD];
    alignas(16) _Float16 Xsl[(size_t)NP * DD];
};

// C0 = X[init_idx]; zero done flag.  grid: KK x DD
__global__ void k_init(const float* __restrict__ X, const int* __restrict__ idx,
                       float* __restrict__ C, int* __restrict__ done) {
    int k = blockIdx.x, d = threadIdx.x;
    C[k * DD + d] = X[(size_t)idx[k] * DD + d];
    if (k == 0 && d == 0) *done = 0;
}

// Once per call: split X into fp16 hi/lo planes in A-fragment order.
// A-frag (16x16x32 f16): lane L of the wave owning 16-point group g16 at
// k-step ks holds X[g16*16 + (L&15)][ks*32 + (L>>4)*8 + j], j=0..7.
// Flat: Xs[(((g16*4)+ks)*64 + L)*8 + j].  grid: NP*DD/8/256 = 8192 blocks.
__global__ void k_split(const float* __restrict__ X, _Float16* __restrict__ Xh,
                        _Float16* __restrict__ Xl) {
    size_t idx = (size_t)blockIdx.x * 256 + threadIdx.x;  // one per 8 elems
    int lane = idx & 63;
    size_t g16k = idx >> 6;
    size_t point = (g16k >> 2) * 16 + (lane & 15);
    int dim0 = (int)(g16k & 3) * 32 + (lane >> 4) * 8;
    const f32x4* s4 = (const f32x4*)(X + point * DD + dim0);
    f32x4 a = s4[0], b = s4[1];
    half8 h, l;
#pragma unroll
    for (int j = 0; j < 4; j++) {
        _Float16 hi = (_Float16)a[j];
        h[j] = hi; l[j] = (_Float16)(a[j] - (float)hi);
    }
#pragma unroll
    for (int j = 0; j < 4; j++) {
        _Float16 hi = (_Float16)b[j];
        h[4 + j] = hi; l[4 + j] = (_Float16)(b[j] - (float)hi);
    }
    *(half8*)(Xh + idx * 8) = h;
    *(half8*)(Xl + idx * 8) = l;
}

// Initial prep: cnorm + hi/lo B-fragment planes for C0; zero counts/cursor.
// B-frag: lane L at (ks, cluster-tile ct) holds C[ct*16+(L&15)][ks*32+(L>>4)*8+j]
// -> flat ((ks*16+ct)*64 + L)*8 + j.  grid: KK x DD
__global__ void k_prep0(const float* __restrict__ C, float* __restrict__ cnorm,
                        _Float16* __restrict__ Ch, _Float16* __restrict__ Cl,
                        int* __restrict__ counts, int* __restrict__ cursor) {
    int k = blockIdx.x, d = threadIdx.x;
    float v = C[k * DD + d];
    _Float16 hi = (_Float16)v;
    int ct = k >> 4, l4 = k & 15, ks = d >> 5, q = (d >> 3) & 3, j = d & 7;
    size_t dst = ((size_t)(ks * 16 + ct) * 64 + (q * 16 + l4)) * 8 + j;
    Ch[dst] = hi;
    Cl[dst] = (_Float16)(v - (float)hi);
    __shared__ float red[DD];
    red[d] = v * v;
    __syncthreads();
    for (int s = DD / 2; s > 0; s >>= 1) {
        if (d < s) red[d] += red[d + s];
        __syncthreads();
    }
    if (d == 0) {
        cnorm[k] = red[0];
        counts[k] = 0;
        cursor[k] = 0;
    }
}

// MFMA assignment + per-block label histogram -> global counts.
// Each wave = 32 points x 256 clusters, fp16 hi/lo 3-term split, fp32 acc.
// Also zeroes shiftsq (stream-ordered: previous upprep already consumed it).
// grid: NP/128 x 256.
__global__ __launch_bounds__(256, 2) void k_assign(
    const _Float16* __restrict__ Xh, const _Float16* __restrict__ Xl,
    const _Float16* __restrict__ Ch, const _Float16* __restrict__ Cl,
    const float* __restrict__ cnorm, float* __restrict__ outlab,
    int* __restrict__ ilab, int* __restrict__ counts,
    float* __restrict__ shiftsq) {
    __shared__ int hist[KK];
    if (blockIdx.x == 0 && threadIdx.x == 0) *shiftsq = 0.0f;
    hist[threadIdx.x] = 0;

    const int wave = threadIdx.x >> 6;
    const int lane = threadIdx.x & 63;
    const int l4 = lane & 15, g = lane >> 4;
    const int g16 = blockIdx.x * 8 + wave * 2;

    f32x4 acc[2][16];
#pragma unroll
    for (int pg = 0; pg < 2; pg++)
#pragma unroll
        for (int ct = 0; ct < 16; ct++) acc[pg][ct] = (f32x4){0.f, 0.f, 0.f, 0.f};

#pragma unroll
    for (int ks = 0; ks < 4; ks++) {
        const size_t a0 = ((size_t)(g16 * 4 + ks) * 64 + lane) * 8;
        const size_t a1 = ((size_t)((g16 + 1) * 4 + ks) * 64 + lane) * 8;
        half8 ah0 = *(const half8*)(Xh + a0);
        half8 al0 = *(const half8*)(Xl + a0);
        half8 ah1 = *(const half8*)(Xh + a1);
        half8 al1 = *(const half8*)(Xl + a1);
#pragma unroll
        for (int ct = 0; ct < 16; ct++) {
            const size_t bo = ((size_t)(ks * 16 + ct) * 64 + lane) * 8;
            half8 bh = *(const half8*)(Ch + bo);
            half8 bl = *(const half8*)(Cl + bo);
            acc[0][ct] = __builtin_amdgcn_mfma_f32_16x16x32_f16(al0, bh, acc[0][ct], 0, 0, 0);
            acc[0][ct] = __builtin_amdgcn_mfma_f32_16x16x32_f16(ah0, bl, acc[0][ct], 0, 0, 0);
            acc[0][ct] = __builtin_amdgcn_mfma_f32_16x16x32_f16(ah0, bh, acc[0][ct], 0, 0, 0);
            acc[1][ct] = __builtin_amdgcn_mfma_f32_16x16x32_f16(al1, bh, acc[1][ct], 0, 0, 0);
            acc[1][ct] = __builtin_amdgcn_mfma_f32_16x16x32_f16(ah1, bl, acc[1][ct], 0, 0, 0);
            acc[1][ct] = __builtin_amdgcn_mfma_f32_16x16x32_f16(ah1, bh, acc[1][ct], 0, 0, 0);
        }
    }

    float cn[16];
#pragma unroll
    for (int ct = 0; ct < 16; ct++) cn[ct] = cnorm[ct * 16 + l4];

    // Packed argmin keys: (monotone(float) << 32) | cluster. NaN -> -inf so
    // NaN beats all finite values; low bits give np's first-index tie-break.
    unsigned long long best[2][4];
#pragma unroll
    for (int pg = 0; pg < 2; pg++)
#pragma unroll
        for (int r = 0; r < 4; r++) best[pg][r] = ~0ull;

#pragma unroll
    for (int pg = 0; pg < 2; pg++)
#pragma unroll
        for (int ct = 0; ct < 16; ct++)
#pragma unroll
            for (int r = 0; r < 4; r++) {
                float s = fmaf(-2.0f, acc[pg][ct][r], cn[ct]);
                if (__builtin_isnan(s)) s = -__builtin_inff();
                unsigned u = __float_as_uint(s);
                unsigned m = (u >> 31) ? ~u : (u ^ 0x80000000u);
                unsigned long long key =
                    ((unsigned long long)m << 32) | (unsigned)(ct * 16 + l4);
                if (key < best[pg][r]) best[pg][r] = key;
            }

    // reduce over the 16 cluster-column lanes (low 4 lane bits)
#pragma unroll
    for (int d = 1; d < 16; d <<= 1)
#pragma unroll
        for (int pg = 0; pg < 2; pg++)
#pragma unroll
            for (int r = 0; r < 4; r++) {
                unsigned long long o = __shfl_xor(best[pg][r], d, 64);
                if (o < best[pg][r]) best[pg][r] = o;
            }

    __syncthreads();  // hist zero visible
    if (l4 == 0) {
#pragma unroll
        for (int pg = 0; pg < 2; pg++)
#pragma unroll
            for (int r = 0; r < 4; r++) {
                int point = blockIdx.x * 128 + wave * 32 + pg * 16 + g * 4 + r;
                int lbl = (int)(best[pg][r] & 0x1ff);
                outlab[point] = (float)lbl;
                ilab[point] = lbl;
                atomicAdd(&hist[lbl], 1);
            }
    }
    __syncthreads();
    int h = hist[threadIdx.x];
    if (h) atomicAdd(&counts[threadIdx.x], h);
}

// Counting-sort scatter. Block = 512 points: LDS histogram (few divergent
// LDS atomics — cheap at this count), redundant prefix of global counts,
// ONE block-aggregated cursor reservation per cluster, then rank & write
// ordlab[pos] = p | (label<<17). Also zeroes sums for k_sum.
// grid: NP/512 = 256 blocks x 256 threads.
__global__ __launch_bounds__(256) void k_scatter(
    const int* __restrict__ ilab, const int* __restrict__ counts,
    int* __restrict__ cursor, int* __restrict__ ordlab,
    float* __restrict__ sums) {
    const int t = threadIdx.x;
    const int b = blockIdx.x;

    // zero sums slice: 256 blocks x 128 floats = KK*DD
    if (t < 128) sums[b * 128 + t] = 0.0f;

    __shared__ int hist[KK];
    __shared__ int pre[KK];
    __shared__ int gbase[KK];
    hist[t] = 0;
    int c = counts[t];
    pre[t] = c;
    __syncthreads();

    const int p0 = b * 512;
    const int la = ilab[p0 + t];
    const int lb = ilab[p0 + 256 + t];
    atomicAdd(&hist[la], 1);
    atomicAdd(&hist[lb], 1);

    // inclusive prefix of counts (Hillis-Steele)
#pragma unroll
    for (int d = 1; d < KK; d <<= 1) {
        int v = (t >= d) ? pre[t - d] : 0;
        __syncthreads();
        pre[t] += v;
        __syncthreads();
    }
    // after these syncs all hist atomics are complete
    int h = hist[t];
    int gb = (pre[t] - c) + (h ? atomicAdd(&cursor[t], h) : 0);
    gbase[t] = gb;
    __syncthreads();
    hist[t] = 0;  // reuse as intra-block rank cursor
    __syncthreads();

    int ra = atomicAdd(&hist[la], 1);
    ordlab[gbase[la] + ra] = (p0 + t) | (la << 17);
    int rb = atomicAdd(&hist[lb], 1);
    ordlab[gbase[lb] + rb] = (p0 + 256 + t) | (lb << 17);
}

// Streaming segmented sum over the cluster-sorted position list.
// Position-balanced (immune to cluster-size skew). Thread = (dim d, parity h);
// U-deep double-buffered row gathers; register accumulator flushed on label
// change (wave-uniform branch) via coalesced global atomicAdd — few per block.
// grid: NP/POSB = 512 blocks x 256 threads.
__global__ __launch_bounds__(256) void k_sum(
    const float* __restrict__ X, const int* __restrict__ ordlab,
    float* __restrict__ sums) {
    const int t = threadIdx.x;
    const int d = t & 127, h = t >> 7;

    __shared__ int sol[POSB];
    sol[t] = ordlab[blockIdx.x * POSB + t];
    __syncthreads();

    const int PP = POSB / 2;  // positions per parity
    float xv[UPIPE], xn[UPIPE];
#pragma unroll
    for (int u = 0; u < UPIPE; u++)
        xv[u] = X[(size_t)(sol[2 * u + h] & 0x1ffff) * DD + d];

    float acc = 0.0f;
    int cur = sol[h] >> 17;

    for (int jb = 0; jb < PP; jb += UPIPE) {
        // issue next batch's gathers (tail clamped to a harmless valid index)
#pragma unroll
        for (int u = 0; u < UPIPE; u++) {
            int nj = jb + u + UPIPE;
            int o = sol[2 * (nj < PP ? nj : PP - 1) + h];
            xn[u] = X[(size_t)(o & 0x1ffff) * DD + d];
        }
        // consume current batch
#pragma unroll
        for (int u = 0; u < UPIPE; u++) {
            int l = sol[2 * (jb + u) + h] >> 17;
            if (l != cur) {
                atomicAdd(&sums[cur * DD + d], acc);
                acc = 0.0f;
                cur = l;
            }
            acc += xv[u];
        }
#pragma unroll
        for (int u = 0; u < UPIPE; u++) xv[u] = xn[u];
    }
    atomicAdd(&sums[cur * DD + d], acc);
}

// newC = sums/counts (0/0 -> NaN, matching jnp); shift^2 block-reduced,
// one atomic per block.  grid: KK*DD/256 x 256
__global__ void k_reduce(const float* __restrict__ sums, const int* __restrict__ counts,
                         const float* __restrict__ C, float* __restrict__ newC,
                         float* __restrict__ shiftsq) {
    const int g = blockIdx.x * 256 + threadIdx.x;
    const int k = g >> 7;
    const int t = threadIdx.x;

    float nc = sums[g] / (float)counts[k];
    newC[g] = nc;
    float diff = nc - C[g];

    __shared__ float red[256];
    red[t] = diff * diff;
    __syncthreads();
    for (int st = 128; st > 0; st >>= 1) {
        if (t < st) red[t] += red[t + st];
        __syncthreads();
    }
    if (t == 0) atomicAdd(shiftsq, red[0]);
}

// Fused convergence check + centroid update + next-iter prep (cnorm + hi/lo
// planes) + zero counts/cursor. NaN shiftsq -> not converged (jnp match).
// Benign done race: all blocks compute the same nd.  grid: KK/2 x 256.
__global__ void k_upprep(const float* __restrict__ newC, float* __restrict__ C,
                         const float* __restrict__ shiftsq, int* __restrict__ done,
                         float* __restrict__ cnorm, _Float16* __restrict__ Ch,
                         _Float16* __restrict__ Cl, int* __restrict__ counts,
                         int* __restrict__ cursor) {
    const int t = threadIdx.x;
    const int k = blockIdx.x * 2 + (t >> 7);
    const int d = t & 127;
    float ss = *shiftsq;
    int nd = (*done != 0) || (ss < TOLSQ);
    float v = nd ? C[k * DD + d] : newC[k * DD + d];
    C[k * DD + d] = v;
    if (blockIdx.x == 0 && t == 0 && nd) *done = 1;
    if (d == 0) {
        counts[k] = 0;
        cursor[k] = 0;
    }

    _Float16 hi = (_Float16)v;
    int ct = k >> 4, l4 = k & 15, ks = d >> 5, q = (d >> 3) & 3, j = d & 7;
    size_t dst = ((size_t)(ks * 16 + ct) * 64 + (q * 16 + l4)) * 8 + j;
    Ch[dst] = hi;
    Cl[dst] = (_Float16)(v - (float)hi);

    __shared__ float red[256];
    red[t] = v * v;
    __syncthreads();
    for (int s = 64; s > 0; s >>= 1) {
        if ((t & 127) < s) red[t] += red[t + s];
        __syncthreads();
    }
    if (d == 0) cnorm[k] = red[t];
}

__global__ void k_final(const float* __restrict__ C, float* __restrict__ out) {
    int i = blockIdx.x * 256 + threadIdx.x;
    out[i] = C[i];
}

extern "C" void kernel_launch(void* const* d_in, const int* in_sizes, int n_in,
                              void* d_out, int out_size, void* d_ws, size_t ws_size,
                              hipStream_t stream) {
    const float* X = (const float*)d_in[0];
    const int* idx = (const int*)d_in[1];
    float* out = (float*)d_out;
    Ws* w = (Ws*)d_ws;

    k_init<<<KK, DD, 0, stream>>>(X, idx, w->C, &w->done);
    k_split<<<(int)((size_t)NP * DD / 8 / 256), 256, 0, stream>>>(X, w->Xsh, w->Xsl);
    k_prep0<<<KK, DD, 0, stream>>>(w->C, w->cnorm, w->Csh, w->Csl, w->counts, w->cursor);

    for (int it = 0; it < MAXIT; it++) {
        k_assign<<<NP / 128, 256, 0, stream>>>(w->Xsh, w->Xsl, w->Csh, w->Csl,
                                               w->cnorm, out, w->ilab, w->counts,
                                               &w->shiftsq);
        k_scatter<<<NP / 512, 256, 0, stream>>>(w->ilab, w->counts, w->cursor,
                                                w->ordlab, w->sums);
        k_sum<<<NP / POSB, 256, 0, stream>>>(X, w->ordlab, w->sums);
        k_reduce<<<KK * DD / 256, 256, 0, stream>>>(w->sums, w->counts, w->C,
                                                    w->newC, &w->shiftsq);
        k_upprep<<<KK / 2, 256, 0, stream>>>(w->newC, w->C, &w->shiftsq, &w->done,
                                             w->cnorm, w->Csh, w->Csl, w->counts,
                                             w->cursor);
    }

    k_final<<<KK * DD / 256, 256, 0, stream>>>(w->C, out + NP);
}